// Round 7
// baseline (76.540 us; speedup 1.0000x reference)
//
#include <hip/hip_runtime.h>
#include <hip/hip_fp16.h>

#define NB 16384     // batch rows
#define ND 256       // d_in (GEMM K)
#define NH 1024      // hidden (GEMM N)
#define NK 16        // sparse fan-in

#define REP 8        // PROBE: loop x8, scale 1/8 (exact pow2) -> fused > fills

using f16x8 = __attribute__((ext_vector_type(8))) _Float16;
using f32x4 = __attribute__((ext_vector_type(4))) float;

__device__ __forceinline__ float fast_tanh(float x) {
    float e = __expf(2.0f * x);
    return 1.0f - 2.0f * __builtin_amdgcn_rcpf(e + 1.0f);
}

__device__ __forceinline__ void scat8(float (&a)[8], int ii, float ww, int d0) {
#pragma unroll
    for (int e = 0; e < 8; ++e)
        if (ii == d0 + e) a[e] += ww;
}

// ---------------------------------------------------------------------------
// Kernel 1: scatter w1 into FRAGMENT-ORDERED dense Wf (f16). (frozen)
// ---------------------------------------------------------------------------
__global__ __launch_bounds__(128) void build_w_kernel(
        const int* __restrict__ idx, const float* __restrict__ w1,
        _Float16* __restrict__ Wf) {
    int t = blockIdx.x * 128 + threadIdx.x;
    int h = t >> 5;
    int g = t & 31;
    int d0 = g << 3;
    const int4*   ip = reinterpret_cast<const int4*>(idx + h * NK);
    const float4* wp = reinterpret_cast<const float4*>(w1 + h * NK);
    float a[8];
#pragma unroll
    for (int e = 0; e < 8; ++e) a[e] = 0.f;
#pragma unroll
    for (int j = 0; j < 4; ++j) {
        int4   I = ip[j];
        float4 V = wp[j];
        scat8(a, I.x, V.x, d0);
        scat8(a, I.y, V.y, d0);
        scat8(a, I.z, V.z, d0);
        scat8(a, I.w, V.w, d0);
    }
    int c  = h >> 4;
    int ml = h & 15;
    int ks = g >> 2;
    int kg = g & 3;
    size_t off = (((size_t)(c * 8 + ks)) * 64 + kg * 16 + ml) * 8;
    f16x8 o;
#pragma unroll
    for (int e = 0; e < 8; ++e) o[e] = (_Float16)a[e];
    *reinterpret_cast<f16x8*>(&Wf[off]) = o;
}

// ---------------------------------------------------------------------------
// Kernel 2: PROBE BUILD — identical to R5 except main loop runs REP(=8) times
// into the same rowpart, scaled 1/REP at the end. Output numerically ~= R5.
// Purpose: push fused past the 40us harness fills into rocprof top-5 so
// MfmaUtil/VALUBusy/Occupancy/VGPR for the steady-state loop become visible.
// ---------------------------------------------------------------------------
__global__ __launch_bounds__(512, 2) void fused_kernel(
        const float* __restrict__ x, const _Float16* __restrict__ Wf,
        const float* __restrict__ b1, const float* __restrict__ w2,
        const float* __restrict__ b2, float* __restrict__ out) {
    __shared__ _Float16 lA[64 * 256];
    __shared__ float red[8 * 64];

    const int t = threadIdx.x;
    const int lane = t & 63;
    const int w = t >> 6;
    const int gm0 = blockIdx.x * 64;
    const int ml = lane & 15;
    const int kg = lane >> 4;
    const int start = ((blockIdx.x >> 3) + w) & 7;

    const int sr  = t >> 3;
    const int sub = t & 7;
    const float4* xsrc = reinterpret_cast<const float4*>(
        x + (size_t)(gm0 + sr) * ND + sub * 32);
    float4 v[8];
#pragma unroll
    for (int j = 0; j < 8; ++j) v[j] = xsrc[j];

    const _Float16* gW = Wf + (size_t)w * 32768 + (size_t)lane * 8;
    f16x8 bA[4], bB[4];
    {
        const _Float16* p0 = gW + start * 4096;
#pragma unroll
        for (int ks = 0; ks < 4; ++ks)
            bA[ks] = *reinterpret_cast<const f16x8*>(p0 + ks * 512);
#pragma unroll
        for (int ks = 0; ks < 4; ++ks)
            bB[ks] = *reinterpret_cast<const f16x8*>(p0 + 2048 + ks * 512);
    }

#pragma unroll
    for (int q = 0; q < 4; ++q) {
        int c = sub * 4 + q;
        f16x8 hh;
        hh[0] = (_Float16)v[2*q].x;   hh[1] = (_Float16)v[2*q].y;
        hh[2] = (_Float16)v[2*q].z;   hh[3] = (_Float16)v[2*q].w;
        hh[4] = (_Float16)v[2*q+1].x; hh[5] = (_Float16)v[2*q+1].y;
        hh[6] = (_Float16)v[2*q+1].z; hh[7] = (_Float16)v[2*q+1].w;
        int a16 = sr * 32 + (c ^ (sr & 7));
        *reinterpret_cast<f16x8*>(&lA[a16 * 8]) = hh;
    }
    __syncthreads();

    f16x8 af[4][8];
#pragma unroll
    for (int mi = 0; mi < 4; ++mi)
#pragma unroll
        for (int ks = 0; ks < 8; ++ks) {
            int r = mi * 16 + ml;
            int c = ks * 4 + kg;
            af[mi][ks] = *reinterpret_cast<const f16x8*>(
                &lA[(r * 32 + (c ^ (r & 7))) * 8]);
        }

    float rowpart[4][4];
#pragma unroll
    for (int mi = 0; mi < 4; ++mi)
#pragma unroll
        for (int r4 = 0; r4 < 4; ++r4) rowpart[mi][r4] = 0.f;

#pragma unroll 1
    for (int rep = 0; rep < REP; ++rep) {
#pragma unroll 1
        for (int nc = 0; nc < 8; ++nc) {
            const int ncc = (start + nc) & 7;
            float b1v = b1[w * 128 + ncc * 16 + ml];
            float w2v = w2[w * 128 + ncc * 16 + ml];

            f32x4 acc[4];
#pragma unroll
            for (int mi = 0; mi < 4; ++mi) acc[mi] = f32x4{0.f, 0.f, 0.f, 0.f};

            const int ncn = (start + nc + 1) & 7;
            const _Float16* pn = gW + ncn * 4096;

            __builtin_amdgcn_s_setprio(1);
#pragma unroll
            for (int ks = 0; ks < 4; ++ks)
#pragma unroll
                for (int mi = 0; mi < 4; ++mi)
                    acc[mi] = __builtin_amdgcn_mfma_f32_16x16x32_f16(
                        af[mi][ks], bA[ks], acc[mi], 0, 0, 0);
            __builtin_amdgcn_s_setprio(0);
#pragma unroll
            for (int ks = 0; ks < 4; ++ks)
                bA[ks] = *reinterpret_cast<const f16x8*>(pn + ks * 512);

            __builtin_amdgcn_s_setprio(1);
#pragma unroll
            for (int ks = 0; ks < 4; ++ks)
#pragma unroll
                for (int mi = 0; mi < 4; ++mi)
                    acc[mi] = __builtin_amdgcn_mfma_f32_16x16x32_f16(
                        af[mi][4 + ks], bB[ks], acc[mi], 0, 0, 0);
            __builtin_amdgcn_s_setprio(0);
#pragma unroll
            for (int ks = 0; ks < 4; ++ks)
                bB[ks] = *reinterpret_cast<const f16x8*>(pn + 2048 + ks * 512);

#pragma unroll
            for (int mi = 0; mi < 4; ++mi)
#pragma unroll
                for (int r4 = 0; r4 < 4; ++r4)
                    rowpart[mi][r4] += fast_tanh(acc[mi][r4] + b1v) * w2v;
        }
    }

    // undo the REP-fold accumulation (exact pow-2 scale)
#pragma unroll
    for (int mi = 0; mi < 4; ++mi)
#pragma unroll
        for (int r4 = 0; r4 < 4; ++r4) rowpart[mi][r4] *= (1.0f / REP);

#pragma unroll
    for (int mi = 0; mi < 4; ++mi)
#pragma unroll
        for (int r4 = 0; r4 < 4; ++r4) {
            float vv = rowpart[mi][r4];
            vv += __shfl_xor(vv, 1);
            vv += __shfl_xor(vv, 2);
            vv += __shfl_xor(vv, 4);
            vv += __shfl_xor(vv, 8);
            rowpart[mi][r4] = vv;
        }
    if (ml == 0) {
#pragma unroll
        for (int mi = 0; mi < 4; ++mi)
#pragma unroll
            for (int r4 = 0; r4 < 4; ++r4)
                red[w * 64 + mi * 16 + kg * 4 + r4] = rowpart[mi][r4];
    }
    __syncthreads();

    if (t < 64) {
        float s = 0.f;
#pragma unroll
        for (int j = 0; j < 8; ++j) s += red[j * 64 + t];
        out[gm0 + t] = fast_tanh(s + b2[0]);
    }
}

extern "C" void kernel_launch(void* const* d_in, const int* in_sizes, int n_in,
                              void* d_out, int out_size, void* d_ws, size_t ws_size,
                              hipStream_t stream) {
    const float* x   = (const float*)d_in[0];
    const int*   idx = (const int*)d_in[1];
    const float* w1  = (const float*)d_in[2];
    const float* b1  = (const float*)d_in[3];
    const float* w2  = (const float*)d_in[4];
    const float* b2  = (const float*)d_in[5];
    float* out = (float*)d_out;

    _Float16* Wf = (_Float16*)d_ws;

    build_w_kernel<<<(NH * 32) / 128, 128, 0, stream>>>(idx, w1, Wf);
    fused_kernel<<<NB / 64, 512, 0, stream>>>(x, Wf, b1, w2, b2, out);
}